// Round 1
// baseline (396.185 us; speedup 1.0000x reference)
//
#include <hip/hip_runtime.h>
#include <hip/hip_cooperative_groups.h>
#include <math.h>

namespace cg = cooperative_groups;

// Problem constants
#define NB   64
#define CC   256
#define TT   64
#define VV   25
#define HID  16
#define NG   5
#define ROWF 1600          // floats per (n,c) pair = T*V
#define ROWF4 400          // float4 per (n,c) pair

// torso joints {0,1,2,3,20} as a bitmask
#define TORSO_MASK 0x10000Fu

// fused-kernel geometry
#define GRID   1024        // cooperative grid: 4 blocks/CU x 256 CU
#define BPB    16          // (n,c) pairs per block = 16384 / 1024
#define CHUNK  4           // pairs staged per LDS chunk in apply phase
#define NCHUNK (BPB / CHUNK)

// fallback (non-cooperative) apply geometry
#define PAIRS 4

// output joint position -> source joint (concat order: TORSO, LH, LL, RH, RL)
// packed LUT: src | (grp<<8)
__constant__ int PERM_LUT[VV] = {
    0|(0<<8), 1|(0<<8), 2|(0<<8), 3|(0<<8), 20|(0<<8),
    8|(1<<8), 9|(1<<8), 10|(1<<8), 11|(1<<8), 23|(1<<8), 24|(1<<8),
    16|(2<<8), 17|(2<<8), 18|(2<<8), 19|(2<<8),
    4|(3<<8), 5|(3<<8), 6|(3<<8), 7|(3<<8), 21|(3<<8), 22|(3<<8),
    12|(4<<8), 13|(4<<8), 14|(4<<8), 15|(4<<8)
};

// ==================== Fused cooperative kernel ====================
// Phase 1: pool torso (streams all of x once, warming L3)
// grid.sync()
// Phase 2: every block redundantly computes the 80 gates for its own n
// Phase 3: scale + permute via LDS staging (x re-read hits L3), write out
__global__ __launch_bounds__(256, 4)
void fused_kernel(const float4* __restrict__ x4,
                  const float* __restrict__ W1s,   // (5,16,256)
                  const float* __restrict__ b1s,   // (5,16)
                  const float* __restrict__ W2s,   // (5,256,16)
                  const float* __restrict__ b2s,   // (5,256)
                  float* __restrict__ avg_g,       // (N*C) workspace
                  float* __restrict__ max_g,       // (N*C) workspace
                  float4* __restrict__ out4)
{
    __shared__ float  lds[CHUNK * ROWF];   // 25.6 KB staging
    __shared__ float4 sAvg[CC / 4];
    __shared__ float4 sMax[CC / 4];
    __shared__ float  sHA[NG * HID];
    __shared__ float  sHM[NG * HID];
    __shared__ float  sg[BPB * NG];        // gates for this block's 16 pairs
    __shared__ int    sLut[VV];

    const int tid  = threadIdx.x;
    const int wave = tid >> 6;
    const int lane = tid & 63;
    const int nc0  = blockIdx.x * BPB;     // first (n,c) pair of this block

    // ---------------- Phase 1: torso pooling, wave per pair ----------------
    // 50-bit replicated torso mask handles the joint wrap within a float4
    const unsigned long long M2 = (unsigned long long)TORSO_MASK
                                | ((unsigned long long)TORSO_MASK << 25);
    #pragma unroll
    for (int p = 0; p < BPB / 4; ++p) {          // 4 pairs per wave
        const int pair  = nc0 + wave * (BPB / 4) + p;
        const int base4 = pair * ROWF4;
        float s = 0.0f;
        float m = -3.4e38f;
        for (int i = lane; i < ROWF4; i += 64) {
            float4 v = x4[base4 + i];
            const int e = 4 * i;
            const int j = e % 25;
            const unsigned bits = (unsigned)((M2 >> j) & 0xFULL);
            if (bits & 1u) { s += v.x; m = fmaxf(m, v.x); }
            if (bits & 2u) { s += v.y; m = fmaxf(m, v.y); }
            if (bits & 4u) { s += v.z; m = fmaxf(m, v.z); }
            if (bits & 8u) { s += v.w; m = fmaxf(m, v.w); }
        }
        #pragma unroll
        for (int off = 32; off >= 1; off >>= 1) {
            s += __shfl_xor(s, off, 64);
            m = fmaxf(m, __shfl_xor(m, off, 64));
        }
        if (lane == 0) {
            avg_g[pair] = s * (1.0f / (TT * 5));
            max_g[pair] = m;
        }
    }

    __threadfence();                 // make pooled values device-visible
    cg::this_grid().sync();          // single grid-wide barrier

    // ---------------- Phase 2: gates for this block's n (redundant x16) ----
    const int n  = nc0 >> 8;         // CC = 256, BPB divides CC
    const int c0 = nc0 & (CC - 1);

    if (tid < 64)       sAvg[tid]      = reinterpret_cast<const float4*>(avg_g + n * CC)[tid];
    else if (tid < 128) sMax[tid - 64] = reinterpret_cast<const float4*>(max_g + n * CC)[tid - 64];
    if (tid < VV) sLut[tid] = PERM_LUT[tid];
    __syncthreads();

    if (tid < 2 * NG * HID) {              // 160 threads: layer-1 dots
        const int type = tid / (NG * HID); // 0 = avg, 1 = max
        const int rem  = tid % (NG * HID); // f*16 + j
        const float4* pv = type ? sMax : sAvg;
        const float4* w  = reinterpret_cast<const float4*>(W1s + rem * CC);
        float h = b1s[rem];
        #pragma unroll 8
        for (int c4 = 0; c4 < CC / 4; ++c4) {
            float4 a = w[c4], b = pv[c4];
            h += a.x * b.x + a.y * b.y + a.z * b.z + a.w * b.w;
        }
        h = fmaxf(h, 0.0f);
        if (type) sHM[rem] = h; else sHA[rem] = h;
    }
    __syncthreads();

    if (tid < BPB * NG) {                  // 80 threads: only the gates we need
        const int q = tid / NG;            // local pair index (channel offset)
        const int f = tid % NG;
        const int c = c0 + q;
        const float4* w2 = reinterpret_cast<const float4*>(W2s + (f * CC + c) * HID);
        float g = 2.0f * b2s[f * CC + c];
        #pragma unroll
        for (int j4 = 0; j4 < HID / 4; ++j4) {
            float4 w = w2[j4];
            const int jb = f * HID + 4 * j4;
            g += w.x * (sHA[jb + 0] + sHM[jb + 0]);
            g += w.y * (sHA[jb + 1] + sHM[jb + 1]);
            g += w.z * (sHA[jb + 2] + sHM[jb + 2]);
            g += w.w * (sHA[jb + 3] + sHM[jb + 3]);
        }
        sg[tid] = 1.0f / (1.0f + expf(-g));   // sg[q*NG + f]
    }
    __syncthreads();

    // ---------------- Phase 3: scale + permute (x re-read hits L3) ---------
    for (int ch = 0; ch < NCHUNK; ++ch) {
        const int base4 = (nc0 + ch * CHUNK) * ROWF4;
        for (int i = tid; i < CHUNK * ROWF4; i += 256)
            reinterpret_cast<float4*>(lds)[i] = x4[base4 + i];
        __syncthreads();
        for (int i = tid; i < CHUNK * ROWF4; i += 256) {
            const int q  = i / ROWF4;
            const int e0 = 4 * (i - q * ROWF4);
            int row = e0 / 25;
            int p   = e0 - row * 25;
            const float* lrow = lds + q * ROWF;
            const float* gq   = sg + (ch * CHUNK + q) * NG;
            float r[4];
            #pragma unroll
            for (int k = 0; k < 4; ++k) {
                const int lut = sLut[p];
                r[k] = lrow[row * 25 + (lut & 0xFF)] * gq[lut >> 8];
                ++p;
                if (p >= 25) { p = 0; ++row; }
            }
            out4[base4 + i] = make_float4(r[0], r[1], r[2], r[3]);
        }
        __syncthreads();
    }
}

// ==================== Fallback: original 3-kernel path ====================
__global__ void pool_kernel(const float4* __restrict__ x4,
                            float* __restrict__ avg_out,
                            float* __restrict__ max_out) {
    const int wave = threadIdx.x >> 6;
    const int lane = threadIdx.x & 63;
    const int pair = blockIdx.x * 4 + wave;
    const int base4 = pair * ROWF4;

    float s = 0.0f;
    float m = -3.4e38f;
    for (int i = lane; i < ROWF4; i += 64) {
        float4 v = x4[base4 + i];
        const int e = 4 * i;
        int j = e % 25;
        float vals[4] = {v.x, v.y, v.z, v.w};
        #pragma unroll
        for (int k = 0; k < 4; ++k) {
            int jj = j + k;
            if (jj >= 25) jj -= 25;
            if ((TORSO_MASK >> jj) & 1u) {
                s += vals[k];
                m = fmaxf(m, vals[k]);
            }
        }
    }
    #pragma unroll
    for (int off = 32; off >= 1; off >>= 1) {
        s += __shfl_xor(s, off, 64);
        m = fmaxf(m, __shfl_xor(m, off, 64));
    }
    if (lane == 0) {
        avg_out[pair] = s * (1.0f / (TT * 5));
        max_out[pair] = m;
    }
}

__global__ void gates_kernel(const float* __restrict__ avg_in,
                             const float* __restrict__ max_in,
                             const float* __restrict__ W1s,
                             const float* __restrict__ b1s,
                             const float* __restrict__ W2s,
                             const float* __restrict__ b2s,
                             float* __restrict__ gates) {
    __shared__ float4 sAvg[CC / 4];
    __shared__ float4 sMax[CC / 4];
    __shared__ float sHA[NG * HID];
    __shared__ float sHM[NG * HID];

    const int n = blockIdx.x;
    const int tid = threadIdx.x;

    if (tid < 64)       sAvg[tid]      = reinterpret_cast<const float4*>(avg_in + n * CC)[tid];
    else if (tid < 128) sMax[tid - 64] = reinterpret_cast<const float4*>(max_in + n * CC)[tid - 64];
    __syncthreads();

    if (tid < 2 * NG * HID) {
        const int type = tid / (NG * HID);
        const int rem  = tid % (NG * HID);
        const float4* p = type ? sMax : sAvg;
        const float4* w = reinterpret_cast<const float4*>(W1s + rem * CC);
        float h = b1s[rem];
        #pragma unroll 8
        for (int c4 = 0; c4 < CC / 4; ++c4) {
            float4 a = w[c4], b = p[c4];
            h += a.x * b.x + a.y * b.y + a.z * b.z + a.w * b.w;
        }
        h = fmaxf(h, 0.0f);
        if (type) sHM[rem] = h; else sHA[rem] = h;
    }
    __syncthreads();

    const int c = tid;
    #pragma unroll
    for (int f = 0; f < NG; ++f) {
        const float4* w2 = reinterpret_cast<const float4*>(W2s + (f * CC + c) * HID);
        float g = 2.0f * b2s[f * CC + c];
        #pragma unroll
        for (int j4 = 0; j4 < HID / 4; ++j4) {
            float4 w = w2[j4];
            const int jb = f * HID + j4 * 4;
            g += w.x * (sHA[jb + 0] + sHM[jb + 0]);
            g += w.y * (sHA[jb + 1] + sHM[jb + 1]);
            g += w.z * (sHA[jb + 2] + sHM[jb + 2]);
            g += w.w * (sHA[jb + 3] + sHM[jb + 3]);
        }
        gates[(n * NG + f) * CC + c] = 1.0f / (1.0f + expf(-g));
    }
}

__global__ void apply_kernel(const float4* __restrict__ x4,
                             const float* __restrict__ gates,
                             float4* __restrict__ out4) {
    __shared__ float lds[PAIRS * ROWF];
    __shared__ float sg[PAIRS * NG];
    __shared__ int sLut[VV];

    const int tid = threadIdx.x;
    const int nc0 = blockIdx.x * PAIRS;
    const int base4 = nc0 * ROWF4;

    #pragma unroll
    for (int i = tid; i < PAIRS * ROWF4; i += 256) {
        reinterpret_cast<float4*>(lds)[i] = x4[base4 + i];
    }
    if (tid < PAIRS * NG) {
        const int q = tid / NG, f = tid % NG;
        const int nc = nc0 + q;
        sg[tid] = gates[((nc >> 8) * NG + f) * CC + (nc & (CC - 1))];
    }
    if (tid < VV) sLut[tid] = PERM_LUT[tid];
    __syncthreads();

    #pragma unroll
    for (int i = tid; i < PAIRS * ROWF4; i += 256) {
        const int q = i / ROWF4;
        const int e0 = 4 * (i - q * ROWF4);
        int row = e0 / 25;
        int p   = e0 - row * 25;
        const float* lrow = lds + q * ROWF;
        const float* gq   = sg + q * NG;
        float r[4];
        #pragma unroll
        for (int k = 0; k < 4; ++k) {
            const int lut = sLut[p];
            r[k] = lrow[row * 25 + (lut & 0xFF)] * gq[lut >> 8];
            ++p;
            if (p >= 25) { p = 0; ++row; }
        }
        out4[base4 + i] = make_float4(r[0], r[1], r[2], r[3]);
    }
}

extern "C" void kernel_launch(void* const* d_in, const int* in_sizes, int n_in,
                              void* d_out, int out_size, void* d_ws, size_t ws_size,
                              hipStream_t stream) {
    const float4* x4  = (const float4*)d_in[0];
    const float*  W1s = (const float*)d_in[1];
    const float*  b1s = (const float*)d_in[2];
    const float*  W2s = (const float*)d_in[3];
    const float*  b2s = (const float*)d_in[4];

    float* avg   = (float*)d_ws;                  // N*C
    float* mx    = avg + NB * CC;                 // N*C
    float* gates = mx + NB * CC;                  // N*5*C (fallback path only)
    float4* o4   = (float4*)d_out;

    void* args[] = { (void*)&x4, (void*)&W1s, (void*)&b1s, (void*)&W2s,
                     (void*)&b2s, (void*)&avg, (void*)&mx, (void*)&o4 };

    hipError_t err = hipLaunchCooperativeKernel(
        reinterpret_cast<void*>(fused_kernel),
        dim3(GRID), dim3(256), args, 0, stream);

    if (err != hipSuccess) {
        (void)hipGetLastError();   // clear error state, fall back to 3 kernels
        pool_kernel<<<(NB * CC) / 4, 256, 0, stream>>>(x4, avg, mx);
        gates_kernel<<<NB, CC, 0, stream>>>(avg, mx, W1s, b1s, W2s, b2s, gates);
        apply_kernel<<<(NB * CC) / PAIRS, 256, 0, stream>>>(x4, gates, o4);
    }
}

// Round 2
// 270.619 us; speedup vs baseline: 1.4640x; 1.4640x over previous
//
#include <hip/hip_runtime.h>
#include <math.h>

// Problem constants
#define NB   64
#define CC   256
#define TT   64
#define VV   25
#define HID  16
#define NG   5
#define ROWF 1600          // floats per (n,c) pair = T*V
#define ROWF4 400          // float4 per (n,c) pair
#define PAIRS 4            // (n,c) pairs per apply block

// torso joints {0,1,2,3,20} as a bitmask
#define TORSO_MASK 0x10000Fu

// output joint position -> source joint (concat order: TORSO, LH, LL, RH, RL)
// packed LUT: src | (grp<<8)
__constant__ int PERM_LUT[VV] = {
    0|(0<<8), 1|(0<<8), 2|(0<<8), 3|(0<<8), 20|(0<<8),
    8|(1<<8), 9|(1<<8), 10|(1<<8), 11|(1<<8), 23|(1<<8), 24|(1<<8),
    16|(2<<8), 17|(2<<8), 18|(2<<8), 19|(2<<8),
    4|(3<<8), 5|(3<<8), 6|(3<<8), 7|(3<<8), 21|(3<<8), 22|(3<<8),
    12|(4<<8), 13|(4<<8), 14|(4<<8), 15|(4<<8)
};

// ---------------- Kernel A: torso pooling, fully coalesced float4 reads ----------------
// One wave per (n,c) pair; 4 waves per block; 4096 blocks (full machine width).
__global__ void pool_kernel(const float4* __restrict__ x4,
                            float* __restrict__ avg_out,
                            float* __restrict__ max_out) {
    const int wave = threadIdx.x >> 6;
    const int lane = threadIdx.x & 63;
    const int pair = blockIdx.x * 4 + wave;      // n*C + c
    const int base4 = pair * ROWF4;

    // 50-bit replicated torso mask handles the joint wrap within a float4
    const unsigned long long M2 = (unsigned long long)TORSO_MASK
                                | ((unsigned long long)TORSO_MASK << 25);
    float s = 0.0f;
    float m = -3.4e38f;
    for (int i = lane; i < ROWF4; i += 64) {
        float4 v = x4[base4 + i];
        const int j = (4 * i) % 25;              // joint of first element
        const unsigned bits = (unsigned)((M2 >> j) & 0xFULL);
        if (bits & 1u) { s += v.x; m = fmaxf(m, v.x); }
        if (bits & 2u) { s += v.y; m = fmaxf(m, v.y); }
        if (bits & 4u) { s += v.z; m = fmaxf(m, v.z); }
        if (bits & 8u) { s += v.w; m = fmaxf(m, v.w); }
    }
    #pragma unroll
    for (int off = 32; off >= 1; off >>= 1) {
        s += __shfl_xor(s, off, 64);
        m = fmaxf(m, __shfl_xor(m, off, 64));
    }
    if (lane == 0) {
        avg_out[pair] = s * (1.0f / (TT * 5));
        max_out[pair] = m;
    }
}

// ---------------- Kernel B: fused gates + apply ----------------
// Block of 256 threads handles PAIRS=4 consecutive channels of one n.
// It recomputes the tiny gate MLP for its own 4 channels (redundant across the
// 64 blocks of each n: ~0.3 GFLOP aggregate, ~2 us on the VALU, fully hidden),
// then does the LDS-staged scale + joint permutation. x re-read hits L3
// (warmed by pool_kernel); writes stream to HBM.
__global__ __launch_bounds__(256)
void applyg_kernel(const float4* __restrict__ x4,
                   const float* __restrict__ avg_g,   // (N,C) pooled
                   const float* __restrict__ max_g,   // (N,C) pooled
                   const float* __restrict__ W1s,     // (5,16,256)
                   const float* __restrict__ b1s,     // (5,16)
                   const float* __restrict__ W2s,     // (5,256,16)
                   const float* __restrict__ b2s,     // (5,256)
                   float4* __restrict__ out4) {
    __shared__ float  lds[PAIRS * ROWF];   // 25.6 KB staging
    __shared__ float4 sAvg[CC / 4];
    __shared__ float4 sMax[CC / 4];
    __shared__ float  sHA[NG * HID];
    __shared__ float  sHM[NG * HID];
    __shared__ float  sg[PAIRS * NG];      // the 20 gates this block needs
    __shared__ int    sLut[VV];

    const int tid  = threadIdx.x;
    const int nc0  = blockIdx.x * PAIRS;   // first (n,c) pair
    const int n    = nc0 >> 8;             // CC = 256
    const int c0   = nc0 & (CC - 1);
    const int base4 = nc0 * ROWF4;

    // coalesced stage of the 4 row-blocks into LDS, plus pooled vectors
    #pragma unroll
    for (int i = tid; i < PAIRS * ROWF4; i += 256) {
        reinterpret_cast<float4*>(lds)[i] = x4[base4 + i];
    }
    if (tid < 64)       sAvg[tid]      = reinterpret_cast<const float4*>(avg_g + n * CC)[tid];
    else if (tid < 128) sMax[tid - 64] = reinterpret_cast<const float4*>(max_g + n * CC)[tid - 64];
    if (tid < VV) sLut[tid] = PERM_LUT[tid];
    __syncthreads();

    // gate MLP layer 1: 160 threads, one hidden unit each (avg & max paths)
    if (tid < 2 * NG * HID) {
        const int type = tid / (NG * HID); // 0 = avg, 1 = max
        const int rem  = tid % (NG * HID); // f*16 + j
        const float4* pv = type ? sMax : sAvg;
        const float4* w  = reinterpret_cast<const float4*>(W1s + rem * CC);
        float h = b1s[rem];
        #pragma unroll 8
        for (int c4 = 0; c4 < CC / 4; ++c4) {
            float4 a = w[c4], b = pv[c4];
            h += a.x * b.x + a.y * b.y + a.z * b.z + a.w * b.w;
        }
        h = fmaxf(h, 0.0f);
        if (type) sHM[rem] = h; else sHA[rem] = h;
    }
    __syncthreads();

    // gate MLP layer 2: only the 20 gates (4 channels x 5 groups) we consume
    if (tid < PAIRS * NG) {
        const int q = tid / NG;            // local channel offset
        const int f = tid % NG;
        const int c = c0 + q;
        const float4* w2 = reinterpret_cast<const float4*>(W2s + (f * CC + c) * HID);
        float g = 2.0f * b2s[f * CC + c];
        #pragma unroll
        for (int j4 = 0; j4 < HID / 4; ++j4) {
            float4 w = w2[j4];
            const int jb = f * HID + 4 * j4;
            g += w.x * (sHA[jb + 0] + sHM[jb + 0]);
            g += w.y * (sHA[jb + 1] + sHM[jb + 1]);
            g += w.z * (sHA[jb + 2] + sHM[jb + 2]);
            g += w.w * (sHA[jb + 3] + sHM[jb + 3]);
        }
        sg[tid] = 1.0f / (1.0f + expf(-g));   // sg[q*NG + f]
    }
    __syncthreads();

    // scale + permute from LDS, coalesced float4 writes
    #pragma unroll
    for (int i = tid; i < PAIRS * ROWF4; i += 256) {
        const int q  = i / ROWF4;
        const int e0 = 4 * (i - q * ROWF4);   // first element index within pair
        int row = e0 / 25;
        int p   = e0 - row * 25;
        const float* lrow = lds + q * ROWF;
        const float* gq   = sg + q * NG;
        float r[4];
        #pragma unroll
        for (int k = 0; k < 4; ++k) {
            const int lut = sLut[p];
            r[k] = lrow[row * 25 + (lut & 0xFF)] * gq[lut >> 8];
            ++p;
            if (p >= 25) { p = 0; ++row; }
        }
        out4[base4 + i] = make_float4(r[0], r[1], r[2], r[3]);
    }
}

extern "C" void kernel_launch(void* const* d_in, const int* in_sizes, int n_in,
                              void* d_out, int out_size, void* d_ws, size_t ws_size,
                              hipStream_t stream) {
    const float4* x4  = (const float4*)d_in[0];
    const float*  W1s = (const float*)d_in[1];
    const float*  b1s = (const float*)d_in[2];
    const float*  W2s = (const float*)d_in[3];
    const float*  b2s = (const float*)d_in[4];

    float* avg = (float*)d_ws;                    // N*C
    float* mx  = avg + NB * CC;                   // N*C

    // Kernel A: one wave per (n,c), 4 waves/block, 4096 blocks
    pool_kernel<<<(NB * CC) / 4, 256, 0, stream>>>(x4, avg, mx);

    // Kernel B: fused gates+apply, 4 channels per block, 4096 blocks
    applyg_kernel<<<(NB * CC) / PAIRS, 256, 0, stream>>>(
        x4, avg, mx, W1s, b1s, W2s, b2s, (float4*)d_out);
}

// Round 4
// 217.964 us; speedup vs baseline: 1.8177x; 1.2416x over previous
//
#include <hip/hip_runtime.h>
#include <math.h>

// Problem constants
#define NB   64
#define CC   256
#define TT   64
#define VV   25
#define HID  16
#define NG   5
#define ROWF 1600          // floats per (n,c) pair = T*V
#define ROWF4 400          // float4 per (n,c) pair
#define PAIRS 2            // (n,c) pairs per apply block (12.8 KB LDS -> 8 blocks/CU)

// torso joints {0,1,2,3,20} as a bitmask
#define TORSO_MASK 0x10000Fu

// native vector type accepted by __builtin_nontemporal_store
typedef float fx4 __attribute__((ext_vector_type(4)));

// output joint position -> source joint (concat order: TORSO, LH, LL, RH, RL)
// packed LUT: src | (grp<<8)
__constant__ int PERM_LUT[VV] = {
    0|(0<<8), 1|(0<<8), 2|(0<<8), 3|(0<<8), 20|(0<<8),
    8|(1<<8), 9|(1<<8), 10|(1<<8), 11|(1<<8), 23|(1<<8), 24|(1<<8),
    16|(2<<8), 17|(2<<8), 18|(2<<8), 19|(2<<8),
    4|(3<<8), 5|(3<<8), 6|(3<<8), 7|(3<<8), 21|(3<<8), 22|(3<<8),
    12|(4<<8), 13|(4<<8), 14|(4<<8), 15|(4<<8)
};

// ---------------- Kernel A: torso pooling, coalesced float4, branchless ----------------
// One wave per (n,c) pair; 4 waves per block; 4096 blocks.
__global__ void pool_kernel(const float4* __restrict__ x4,
                            float* __restrict__ avg_out,
                            float* __restrict__ max_out) {
    const int wave = threadIdx.x >> 6;
    const int lane = threadIdx.x & 63;
    const int pair = blockIdx.x * 4 + wave;      // n*C + c
    const int base4 = pair * ROWF4;

    // 50-bit replicated torso mask handles the joint wrap within a float4
    const unsigned long long M2 = (unsigned long long)TORSO_MASK
                                | ((unsigned long long)TORSO_MASK << 25);
    const float NEG = -3.4e38f;
    float s = 0.0f;
    float m = NEG;
    for (int i = lane; i < ROWF4; i += 64) {
        float4 v = x4[base4 + i];
        const int j = (4 * i) % 25;              // joint of first element
        const unsigned bits = (unsigned)((M2 >> j) & 0xFULL);
        // branchless: cndmask + add/max, no exec-mask toggling
        s += (bits & 1u) ? v.x : 0.0f;
        s += (bits & 2u) ? v.y : 0.0f;
        s += (bits & 4u) ? v.z : 0.0f;
        s += (bits & 8u) ? v.w : 0.0f;
        m = fmaxf(m, (bits & 1u) ? v.x : NEG);
        m = fmaxf(m, (bits & 2u) ? v.y : NEG);
        m = fmaxf(m, (bits & 4u) ? v.z : NEG);
        m = fmaxf(m, (bits & 8u) ? v.w : NEG);
    }
    #pragma unroll
    for (int off = 32; off >= 1; off >>= 1) {
        s += __shfl_xor(s, off, 64);
        m = fmaxf(m, __shfl_xor(m, off, 64));
    }
    if (lane == 0) {
        avg_out[pair] = s * (1.0f / (TT * 5));
        max_out[pair] = m;
    }
}

// ---------------- Kernel B: gate MLPs (one block per n, 64 blocks) ----------------
__global__ void gates_kernel(const float* __restrict__ avg_in,
                             const float* __restrict__ max_in,
                             const float* __restrict__ W1s,   // (5,16,256)
                             const float* __restrict__ b1s,   // (5,16)
                             const float* __restrict__ W2s,   // (5,256,16)
                             const float* __restrict__ b2s,   // (5,256)
                             float* __restrict__ gates) {     // (N,5,256)
    __shared__ float4 sAvg[CC / 4];
    __shared__ float4 sMax[CC / 4];
    __shared__ float sHA[NG * HID];
    __shared__ float sHM[NG * HID];

    const int n = blockIdx.x;
    const int tid = threadIdx.x;

    if (tid < 64)       sAvg[tid]      = reinterpret_cast<const float4*>(avg_in + n * CC)[tid];
    else if (tid < 128) sMax[tid - 64] = reinterpret_cast<const float4*>(max_in + n * CC)[tid - 64];
    __syncthreads();

    if (tid < 2 * NG * HID) {              // 160 threads
        const int type = tid / (NG * HID); // 0 = avg, 1 = max
        const int rem  = tid % (NG * HID); // f*16 + j
        const float4* p = type ? sMax : sAvg;
        const float4* w = reinterpret_cast<const float4*>(W1s + rem * CC);
        float h = b1s[rem];
        #pragma unroll 8
        for (int c4 = 0; c4 < CC / 4; ++c4) {
            float4 a = w[c4], b = p[c4];
            h += a.x * b.x + a.y * b.y + a.z * b.z + a.w * b.w;
        }
        h = fmaxf(h, 0.0f);
        if (type) sHM[rem] = h; else sHA[rem] = h;
    }
    __syncthreads();

    const int c = tid;
    #pragma unroll
    for (int f = 0; f < NG; ++f) {
        const float4* w2 = reinterpret_cast<const float4*>(W2s + (f * CC + c) * HID);
        float g = 2.0f * b2s[f * CC + c];
        #pragma unroll
        for (int j4 = 0; j4 < HID / 4; ++j4) {
            float4 w = w2[j4];
            const int jb = f * HID + j4 * 4;
            g += w.x * (sHA[jb + 0] + sHM[jb + 0]);
            g += w.y * (sHA[jb + 1] + sHM[jb + 1]);
            g += w.z * (sHA[jb + 2] + sHM[jb + 2]);
            g += w.w * (sHA[jb + 3] + sHM[jb + 3]);
        }
        gates[(n * NG + f) * CC + c] = 1.0f / (1.0f + expf(-g));
    }
}

// ---------------- Kernel C: LDS-staged scale + joint permutation ----------------
// PAIRS=2 pairs per 256-thread block: 12.8 KB LDS -> 8 blocks/CU (32-wave cap).
// Output uses nontemporal stores so the 103 MB write stream does not evict the
// L3-resident x (warmed by pool_kernel) mid-kernel.
__global__ __launch_bounds__(256)
void apply_kernel(const float4* __restrict__ x4,
                  const float* __restrict__ gates,
                  fx4* __restrict__ out4) {
    __shared__ float lds[PAIRS * ROWF];
    __shared__ float sg[PAIRS * NG];
    __shared__ int sLut[VV];

    const int tid = threadIdx.x;
    const int nc0 = blockIdx.x * PAIRS;
    const int base4 = nc0 * ROWF4;

    #pragma unroll
    for (int i = tid; i < PAIRS * ROWF4; i += 256) {
        reinterpret_cast<float4*>(lds)[i] = x4[base4 + i];
    }
    if (tid < PAIRS * NG) {                 // 10 gate values
        const int q = tid / NG, f = tid % NG;
        const int nc = nc0 + q;
        sg[tid] = gates[((nc >> 8) * NG + f) * CC + (nc & (CC - 1))];
    }
    if (tid < VV) sLut[tid] = PERM_LUT[tid];
    __syncthreads();

    #pragma unroll
    for (int i = tid; i < PAIRS * ROWF4; i += 256) {
        const int q = i / ROWF4;
        const int e0 = 4 * (i - q * ROWF4);   // first element index within pair
        int row = e0 / 25;
        int p   = e0 - row * 25;
        const float* lrow = lds + q * ROWF;
        const float* gq   = sg + q * NG;
        fx4 r;
        #pragma unroll
        for (int k = 0; k < 4; ++k) {
            const int lut = sLut[p];
            r[k] = lrow[row * 25 + (lut & 0xFF)] * gq[lut >> 8];
            ++p;
            if (p >= 25) { p = 0; ++row; }
        }
        __builtin_nontemporal_store(r, &out4[base4 + i]);
    }
}

extern "C" void kernel_launch(void* const* d_in, const int* in_sizes, int n_in,
                              void* d_out, int out_size, void* d_ws, size_t ws_size,
                              hipStream_t stream) {
    const float* x   = (const float*)d_in[0];
    const float* W1s = (const float*)d_in[1];
    const float* b1s = (const float*)d_in[2];
    const float* W2s = (const float*)d_in[3];
    const float* b2s = (const float*)d_in[4];

    float* avg   = (float*)d_ws;                  // N*C
    float* mx    = avg + NB * CC;                 // N*C
    float* gates = mx + NB * CC;                  // N*5*C

    // Kernel A: one wave per (n,c), 4 waves/block
    pool_kernel<<<(NB * CC) / 4, 256, 0, stream>>>(
        (const float4*)x, avg, mx);

    // Kernel B: one block per n
    gates_kernel<<<NB, CC, 0, stream>>>(avg, mx, W1s, b1s, W2s, b2s, gates);

    // Kernel C: PAIRS (n,c) pairs per block, 8192 blocks
    apply_kernel<<<(NB * CC) / PAIRS, 256, 0, stream>>>(
        (const float4*)x, gates, (fx4*)d_out);
}